// Round 11
// baseline (682.581 us; speedup 1.0000x reference)
//
#include <hip/hip_runtime.h>
#include <stdint.h>

// ---------------------------------------------------------------------------
// MD5Surrogate: 64-round scan of 3-layer MLP (22->256->256->16), B=16384.
// fp32 in/out. R11: state NEVER touches LDS — W3 output rows permuted in
// pack_w so each lane's MFMA C-output (4 features x batch ln) plus one
// __shfl_xor(.,32) from its partner lane forms the L1 B-fragment directly.
// x-buffers deleted -> LDS 60.9->42.5 KB -> 3 blocks/CU (12 waves/CU).
// Word/rinfo features built via cndmask from msg LDS + constants.
// Keeps: NG=2 row groups, 2 barriers/round, redundant L3 on all waves,
// A&S 7.1.25 gelu, bias-in-accumulator, packed bf16 weights in d_ws.
// ---------------------------------------------------------------------------

using bf16x8   = __attribute__((ext_vector_type(8))) __bf16;
using floatx4  = __attribute__((ext_vector_type(4))) float;
using ushort4v = __attribute__((ext_vector_type(4))) unsigned short;

__constant__ int c_sched[64] = {
  0,1,2,3,4,5,6,7,8,9,10,11,12,13,14,15,
  1,6,11,0,5,10,15,4,9,14,3,8,13,2,7,12,
  5,8,11,14,1,4,7,10,13,0,3,6,9,12,15,2,
  0,7,14,5,12,3,10,1,8,15,6,13,4,11,2,9
};
__constant__ float c_shift[64] = {
  7,12,17,22,7,12,17,22,7,12,17,22,7,12,17,22,
  5,9,14,20,5,9,14,20,5,9,14,20,5,9,14,20,
  4,11,16,23,4,11,16,23,4,11,16,23,4,11,16,23,
  6,10,15,21,6,10,15,21,6,10,15,21,6,10,15,21
};

__device__ __forceinline__ unsigned short bfbits(__bf16 b) {
  union { __bf16 b; unsigned short u; } v; v.b = b; return v.u;
}
__device__ __forceinline__ float bf2f(unsigned short h) {
  union { unsigned u; float f; } v; v.u = ((unsigned)h) << 16;
  return v.f;
}
__device__ __forceinline__ int pack2(unsigned short lo16, unsigned short hi16) {
  return (int)(((unsigned)hi16 << 16) | (unsigned)lo16);
}
// gelu via A&S 7.1.25 (|eps|<=2.5e-5), constants folded, exp2-scaled
__device__ __forceinline__ float gelu_f(float x) {
  float ax = fabsf(x);
  float t  = __builtin_amdgcn_rcpf(__builtin_fmaf(0.33270222f, ax, 1.0f));
  float e  = __builtin_amdgcn_exp2f(x * x * -0.72134752f);
  float poly = t * __builtin_fmaf(t, __builtin_fmaf(t, 0.7478556f, -0.0958798f),
                                  0.3480242f);
  float er = __builtin_fmaf(-poly, e, 1.0f);
  er = copysignf(er, x);
  float hx = 0.5f * x;
  return __builtin_fmaf(hx, er, hx);
}
__device__ __forceinline__ floatx4 mfma16(bf16x8 a, bf16x8 b, floatx4 c) {
  return __builtin_amdgcn_mfma_f32_16x16x32_bf16(a, b, c, 0, 0, 0);
}

// Build next-round L1 B-fragment (hi+lo, 4 ints each) from this lane's fp32
// state quad s plus its xor-32 partner's quad; q=2 lanes get word+rinfo,
// q=3 lanes get zeros (k=24..31 pad).
__device__ __forceinline__ void build_frag(int* fh, int* fl, floatx4 s,
                                           int w01, int w23, int wl01, int wl23,
                                           int i01h, int i01l,
                                           bool isQ2, bool isQ3) {
  unsigned short h0 = bfbits((__bf16)s[0]);
  unsigned short h1 = bfbits((__bf16)s[1]);
  unsigned short h2 = bfbits((__bf16)s[2]);
  unsigned short h3 = bfbits((__bf16)s[3]);
  unsigned short l0 = bfbits((__bf16)(s[0] - bf2f(h0)));
  unsigned short l1 = bfbits((__bf16)(s[1] - bf2f(h1)));
  unsigned short l2 = bfbits((__bf16)(s[2] - bf2f(h2)));
  unsigned short l3 = bfbits((__bf16)(s[3] - bf2f(h3)));
  int oh0 = pack2(h0, h1), oh1 = pack2(h2, h3);
  int ol0 = pack2(l0, l1), ol1 = pack2(l2, l3);
  int th0 = __shfl_xor(oh0, 32);
  int th1 = __shfl_xor(oh1, 32);
  int tl0 = __shfl_xor(ol0, 32);
  int tl1 = __shfl_xor(ol1, 32);
  fh[0] = isQ3 ? 0 : (isQ2 ? w01  : oh0);
  fh[1] = isQ3 ? 0 : (isQ2 ? w23  : oh1);
  fh[2] = isQ3 ? 0 : (isQ2 ? i01h : th0);
  fh[3] = isQ3 ? 0 : (isQ2 ? 0    : th1);
  fl[0] = isQ3 ? 0 : (isQ2 ? wl01 : ol0);
  fl[1] = isQ3 ? 0 : (isQ2 ? wl23 : ol1);
  fl[2] = isQ3 ? 0 : (isQ2 ? i01l : tl0);
  fl[3] = isQ3 ? 0 : (isQ2 ? 0    : tl1);
}

// ---------------------------------------------------------------------------
// Packed-weight layout: fragment = 64 lanes x 8 bf16. A[m][k]: m=lane&15,
// k=8*(lane>>4)+j.
//   P1 (r*16+t): W1[r][k][16t+m] (k>=22 -> 0)          [unchanged]
//   P2 ((r*16+t)*8+c): W2[r][32c+k'][16t+m]            [unchanged]
//   P3 (r*8+c): W3[r][32c+k'][fm(m)]  with row perm
//       fm(m) = 8*((m>>2)&1) + 4*(m>>3) + (m&3)
//   so lane (q,ln) C-output elem e = state feature 8*(q&1)+4*(q>>1)+e.
// ---------------------------------------------------------------------------
#define N1G (64*16*64)
#define N2G (64*16*8*64)
#define N3G (64*8*64)

__global__ void pack_w(const float* __restrict__ W1,
                       const float* __restrict__ W2,
                       const float* __restrict__ W3,
                       unsigned short* __restrict__ P) {
  int gid = blockIdx.x * blockDim.x + threadIdx.x;
  if (gid >= N1G + N2G + N3G) return;
  unsigned short v[8];
  unsigned short* dst;
  if (gid < N1G) {
    int lane = gid & 63, t = (gid >> 6) & 15, r = gid >> 10;
    int qq = lane >> 4, mm = lane & 15;
    #pragma unroll
    for (int j = 0; j < 8; ++j) {
      int k = 8*qq + j;
      v[j] = (k < 22) ? bfbits((__bf16)W1[(r*22 + k)*256 + 16*t + mm]) : (unsigned short)0;
    }
    dst = P + (size_t)gid * 8;
  } else if (gid < N1G + N2G) {
    int g = gid - N1G;
    int lane = g & 63, c = (g >> 6) & 7, t = (g >> 9) & 15, r = g >> 13;
    int qq = lane >> 4, mm = lane & 15;
    #pragma unroll
    for (int j = 0; j < 8; ++j) {
      int k = 32*c + 8*qq + j;
      v[j] = bfbits((__bf16)W2[((size_t)r*256 + k)*256 + 16*t + mm]);
    }
    dst = P + (size_t)(N1G + g) * 8;
  } else {
    int g = gid - N1G - N2G;
    int lane = g & 63, c = (g >> 6) & 7, r = g >> 9;
    int qq = lane >> 4, mm = lane & 15;
    int fm = 8*((mm >> 2) & 1) + 4*(mm >> 3) + (mm & 3);   // row perm
    #pragma unroll
    for (int j = 0; j < 8; ++j) {
      int k = 32*c + 8*qq + j;
      v[j] = bfbits((__bf16)W3[(r*256 + k)*16 + fm]);
    }
    dst = P + (size_t)(N1G + N2G + g) * 8;
  }
  ushort4v lo = { v[0],v[1],v[2],v[3] }, hi = { v[4],v[5],v[6],v[7] };
  *(ushort4v*)dst = lo;
  *(ushort4v*)(dst + 4) = hi;
}

// ---------------------------------------------------------------------------
#define NG 2     // row-groups per block
#define SH 264   // h row stride (ushorts): 528B rows, 16B-aligned
#define SM 68    // msg row stride (ushorts): 136B rows, 8B-aligned

__global__ __launch_bounds__(256, 3) void md5_main(
    const float* __restrict__ msg,   // (16384,64)
    const float* __restrict__ st0,   // (16384,16)
    const float* __restrict__ b1,    // (64,256)
    const float* __restrict__ b2,    // (64,256)
    const float* __restrict__ b3,    // (64,16)
    const unsigned short* __restrict__ P,
    float* __restrict__ out)         // (16384,16)
{
  __shared__ unsigned short hA[NG][16][SH], hB[NG][16][SH];
  __shared__ unsigned short msgb[NG*16][SM], msgl[NG*16][SM];

  const int tid  = threadIdx.x;
  const int wv   = tid >> 6;
  const int lane = tid & 63;
  const int q    = lane >> 4;
  const int ln   = lane & 15;
  const int row0 = blockIdx.x * (NG*16);
  const int oPerm = 8*(q & 1) + 4*(q >> 1);   // this lane's feature base
  const bool isQ2 = (q == 2), isQ3 = (q == 3);

  const unsigned short* P1 = P;
  const unsigned short* P2 = P + (size_t)N1G * 8;
  const unsigned short* P3 = P + (size_t)(N1G + N2G) * 8;

  // msg preload (hi/lo split): 32 rows x 64 = 2048 elems / 256 thr = 8 each
  {
    int idx = tid * 8, rr = idx >> 6, cc = idx & 63;
    floatx4 v0 = *(const floatx4*)(msg + (size_t)(row0 + rr)*64 + cc);
    floatx4 v1 = *(const floatx4*)(msg + (size_t)(row0 + rr)*64 + cc + 4);
    #pragma unroll
    for (int j = 0; j < 4; ++j) {
      unsigned short h0 = bfbits((__bf16)v0[j]);
      unsigned short h1 = bfbits((__bf16)v1[j]);
      msgb[rr][cc + j]     = h0;
      msgb[rr][cc + 4 + j] = h1;
      msgl[rr][cc + j]     = bfbits((__bf16)(v0[j] - bf2f(h0)));
      msgl[rr][cc + 4 + j] = bfbits((__bf16)(v1[j] - bf2f(h1)));
    }
  }
  __syncthreads();

  // L1 B-fragments for the CURRENT round, hi+lo, per group (registers)
  int fxh[NG][4], fxl[NG][4];

  // init: build round-0 fragments from st0 + msg word 0 + rinfo 0
  {
    int sc = c_sched[0];
    float i1 = c_shift[0] * 0.04f;
    unsigned short i1h = bfbits((__bf16)i1);
    unsigned short i1l = bfbits((__bf16)(i1 - bf2f(i1h)));
    int i01h = pack2(0, i1h);   // i0 = 0 at round 0
    int i01l = pack2(0, i1l);
    #pragma unroll
    for (int g = 0; g < NG; ++g) {
      floatx4 s = *(const floatx4*)(st0 + (size_t)(row0 + g*16 + ln)*16 + oPerm);
      int2 wh = *(const int2*)&msgb[g*16 + ln][4*sc];
      int2 wl = *(const int2*)&msgl[g*16 + ln][4*sc];
      build_frag(fxh[g], fxl[g], s, wh.x, wh.y, wl.x, wl.y, i01h, i01l, isQ2, isQ3);
    }
  }

  #pragma unroll 1
  for (int r = 0; r < 64; ++r) {
    // -------- Layer 1: x (regs) @ W1 -> h1 (bf16, shared) --------
    floatx4 bb1[4];
    bf16x8  a1[4];
    const unsigned short* p1 = P1 + ((size_t)(r*16 + 4*wv)*64 + lane)*8;
    #pragma unroll
    for (int tt = 0; tt < 4; ++tt) {
      a1[tt]  = *(const bf16x8*)(p1 + (size_t)tt*512);
      bb1[tt] = *(const floatx4*)(b1 + r*256 + (4*wv + tt)*16 + 4*q);
    }
    bf16x8 xh_[NG], xl_[NG];
    #pragma unroll
    for (int g = 0; g < NG; ++g) {
      union { int i[4]; bf16x8 v; } uh, ul;
      #pragma unroll
      for (int k = 0; k < 4; ++k) { uh.i[k] = fxh[g][k]; ul.i[k] = fxl[g][k]; }
      xh_[g] = uh.v; xl_[g] = ul.v;
    }
    #pragma unroll
    for (int tt = 0; tt < 4; ++tt) {
      int f0 = (4*wv + tt)*16 + 4*q;
      #pragma unroll
      for (int g = 0; g < NG; ++g) {
        floatx4 acc = bb1[tt];
        acc = mfma16(a1[tt], xl_[g], acc);
        acc = mfma16(a1[tt], xh_[g], acc);
        ushort4v h4;
        #pragma unroll
        for (int e = 0; e < 4; ++e) h4[e] = bfbits((__bf16)gelu_f(acc[e]));
        *(ushort4v*)&hA[g][ln][f0] = h4;
      }
    }
    __syncthreads();                       // (B) h1 ready; hB free

    // -------- Layer 2: h1 @ W2 -> h2 (bf16, shared) --------
    // hoisted: L3 A-frags, b3 (perm gather), b2 biases, next-round word data
    bf16x8 a3[8];
    {
      const unsigned short* p3 = P3 + ((size_t)(r*8)*64 + lane)*8;
      #pragma unroll
      for (int c = 0; c < 8; ++c) a3[c] = *(const bf16x8*)(p3 + (size_t)c*512);
    }
    floatx4 bb3 = *(const floatx4*)(b3 + r*16 + oPerm);
    floatx4 bb2[4];
    #pragma unroll
    for (int tt = 0; tt < 4; ++tt)
      bb2[tt] = *(const floatx4*)(b2 + r*256 + (4*wv + tt)*16 + 4*q);

    int2 wh[NG], wl[NG];
    int i01h = 0, i01l = 0;
    if (r < 63) {
      int sc = c_sched[r+1];
      float i0 = (float)(r+1) * 0.015625f;          // exact in bf16
      float i1 = c_shift[r+1] * 0.04f;
      unsigned short i1h = bfbits((__bf16)i1);
      unsigned short i1l = bfbits((__bf16)(i1 - bf2f(i1h)));
      i01h = pack2(bfbits((__bf16)i0), i1h);
      i01l = pack2(0, i1l);
      #pragma unroll
      for (int g = 0; g < NG; ++g) {
        wh[g] = *(const int2*)&msgb[g*16 + ln][4*sc];
        wl[g] = *(const int2*)&msgl[g*16 + ln][4*sc];
      }
    }

    bf16x8 Bf[NG][8];
    #pragma unroll
    for (int g = 0; g < NG; ++g)
      #pragma unroll
      for (int c = 0; c < 8; ++c) Bf[g][c] = *(const bf16x8*)&hA[g][ln][32*c + 8*q];

    const unsigned short* p2 = P2 + ((size_t)((r*16 + 4*wv)*8)*64 + lane)*8;
    #pragma unroll
    for (int tt = 0; tt < 4; ++tt) {
      bf16x8 a2[8];
      #pragma unroll
      for (int c = 0; c < 8; ++c)
        a2[c] = *(const bf16x8*)(p2 + (size_t)(tt*8 + c)*512);
      int f0 = (4*wv + tt)*16 + 4*q;
      #pragma unroll
      for (int g = 0; g < NG; ++g) {
        floatx4 acc = bb2[tt];
        #pragma unroll
        for (int c = 0; c < 8; ++c) acc = mfma16(a2[c], Bf[g][c], acc);
        ushort4v h4;
        #pragma unroll
        for (int e = 0; e < 4; ++e) h4[e] = bfbits((__bf16)gelu_f(acc[e]));
        *(ushort4v*)&hB[g][ln][f0] = h4;
      }
    }
    __syncthreads();                       // (C) h2 ready

    // -------- Layer 3 (redundant on every wave): h2 @ W3p -> state --------
    // C-output: lane (q,ln) elem e = feature oPerm+e of batch ln (perm pack)
    #pragma unroll
    for (int g = 0; g < NG; ++g) {
      floatx4 s = bb3;
      #pragma unroll
      for (int c = 0; c < 8; ++c) {
        bf16x8 bh = *(const bf16x8*)&hB[g][ln][32*c + 8*q];
        s = mfma16(a3[c], bh, s);
      }
      if (r == 63) {
        if (wv == 0)
          *(floatx4*)(out + (size_t)(row0 + g*16 + ln)*16 + oPerm) = s;
      } else {
        build_frag(fxh[g], fxl[g], s, wh[g].x, wh[g].y, wl[g].x, wl[g].y,
                   i01h, i01l, isQ2, isQ3);
      }
    }
    // no barrier here: next L1 uses only registers (fxh/fxl)
  }
}

// ---------------------------------------------------------------------------
extern "C" void kernel_launch(void* const* d_in, const int* in_sizes, int n_in,
                              void* d_out, int out_size, void* d_ws, size_t ws_size,
                              hipStream_t stream) {
  const float* msg = (const float*)d_in[0];
  const float* st0 = (const float*)d_in[1];
  const float* W1  = (const float*)d_in[2];
  const float* b1  = (const float*)d_in[3];
  const float* W2  = (const float*)d_in[4];
  const float* b2  = (const float*)d_in[5];
  const float* W3  = (const float*)d_in[6];
  const float* b3  = (const float*)d_in[7];
  float* out = (float*)d_out;
  (void)in_sizes; (void)n_in; (void)out_size; (void)ws_size;

  unsigned short* P = (unsigned short*)d_ws;
  const int totalGroups = N1G + N2G + N3G;   // 622592
  pack_w<<<(totalGroups + 255) / 256, 256, 0, stream>>>(W1, W2, W3, P);
  md5_main<<<512, 256, 0, stream>>>(msg, st0, b1, b2, b3, P, out);
}

// Round 12
// 484.010 us; speedup vs baseline: 1.4103x; 1.4103x over previous
//
#include <hip/hip_runtime.h>
#include <stdint.h>

// ---------------------------------------------------------------------------
// MD5Surrogate: 64-round scan of 3-layer MLP (22->256->256->16), B=16384.
// fp32 in/out. R12 = R11 (register-resident state via W3 row perm + shfl_xor,
// verified bit-identical) with the VGPR spill fixed:
//   * Bf fragments read from LDS per-MFMA (no 64-reg preload)
//   * a3 loaded AFTER barrier C (transient), not hoisted
//   * build_frag returns by value
// Live set ~110 VGPR < 168 cap at 3 blocks/CU (LDS 42.5KB). 2 barriers/round.
// ---------------------------------------------------------------------------

using bf16x8   = __attribute__((ext_vector_type(8))) __bf16;
using floatx4  = __attribute__((ext_vector_type(4))) float;
using ushort4v = __attribute__((ext_vector_type(4))) unsigned short;

__constant__ int c_sched[64] = {
  0,1,2,3,4,5,6,7,8,9,10,11,12,13,14,15,
  1,6,11,0,5,10,15,4,9,14,3,8,13,2,7,12,
  5,8,11,14,1,4,7,10,13,0,3,6,9,12,15,2,
  0,7,14,5,12,3,10,1,8,15,6,13,4,11,2,9
};
__constant__ float c_shift[64] = {
  7,12,17,22,7,12,17,22,7,12,17,22,7,12,17,22,
  5,9,14,20,5,9,14,20,5,9,14,20,5,9,14,20,
  4,11,16,23,4,11,16,23,4,11,16,23,4,11,16,23,
  6,10,15,21,6,10,15,21,6,10,15,21,6,10,15,21
};

__device__ __forceinline__ unsigned short bfbits(__bf16 b) {
  union { __bf16 b; unsigned short u; } v; v.b = b; return v.u;
}
__device__ __forceinline__ float bf2f(unsigned short h) {
  union { unsigned u; float f; } v; v.u = ((unsigned)h) << 16;
  return v.f;
}
__device__ __forceinline__ int pack2(unsigned short lo16, unsigned short hi16) {
  return (int)(((unsigned)hi16 << 16) | (unsigned)lo16);
}
// gelu via A&S 7.1.25 (|eps|<=2.5e-5), constants folded, exp2-scaled
__device__ __forceinline__ float gelu_f(float x) {
  float ax = fabsf(x);
  float t  = __builtin_amdgcn_rcpf(__builtin_fmaf(0.33270222f, ax, 1.0f));
  float e  = __builtin_amdgcn_exp2f(x * x * -0.72134752f);
  float poly = t * __builtin_fmaf(t, __builtin_fmaf(t, 0.7478556f, -0.0958798f),
                                  0.3480242f);
  float er = __builtin_fmaf(-poly, e, 1.0f);
  er = copysignf(er, x);
  float hx = 0.5f * x;
  return __builtin_fmaf(hx, er, hx);
}
__device__ __forceinline__ floatx4 mfma16(bf16x8 a, bf16x8 b, floatx4 c) {
  return __builtin_amdgcn_mfma_f32_16x16x32_bf16(a, b, c, 0, 0, 0);
}

struct Frag { int h[4]; int l[4]; };
// Build next-round L1 B-fragment from this lane's fp32 state quad + xor-32
// partner's; q=2 lanes carry word+rinfo, q=3 lanes zeros (k pad).
__device__ __forceinline__ Frag build_frag(floatx4 s,
                                           int w01, int w23, int wl01, int wl23,
                                           int i01h, int i01l,
                                           bool isQ2, bool isQ3) {
  unsigned short h0 = bfbits((__bf16)s[0]);
  unsigned short h1 = bfbits((__bf16)s[1]);
  unsigned short h2 = bfbits((__bf16)s[2]);
  unsigned short h3 = bfbits((__bf16)s[3]);
  unsigned short l0 = bfbits((__bf16)(s[0] - bf2f(h0)));
  unsigned short l1 = bfbits((__bf16)(s[1] - bf2f(h1)));
  unsigned short l2 = bfbits((__bf16)(s[2] - bf2f(h2)));
  unsigned short l3 = bfbits((__bf16)(s[3] - bf2f(h3)));
  int oh0 = pack2(h0, h1), oh1 = pack2(h2, h3);
  int ol0 = pack2(l0, l1), ol1 = pack2(l2, l3);
  int th0 = __shfl_xor(oh0, 32);
  int th1 = __shfl_xor(oh1, 32);
  int tl0 = __shfl_xor(ol0, 32);
  int tl1 = __shfl_xor(ol1, 32);
  Frag f;
  f.h[0] = isQ3 ? 0 : (isQ2 ? w01  : oh0);
  f.h[1] = isQ3 ? 0 : (isQ2 ? w23  : oh1);
  f.h[2] = isQ3 ? 0 : (isQ2 ? i01h : th0);
  f.h[3] = isQ3 ? 0 : (isQ2 ? 0    : th1);
  f.l[0] = isQ3 ? 0 : (isQ2 ? wl01 : ol0);
  f.l[1] = isQ3 ? 0 : (isQ2 ? wl23 : ol1);
  f.l[2] = isQ3 ? 0 : (isQ2 ? i01l : tl0);
  f.l[3] = isQ3 ? 0 : (isQ2 ? 0    : tl1);
  return f;
}
__device__ __forceinline__ bf16x8 frag2v(const int* p) {
  union { int i[4]; bf16x8 v; } u;
  u.i[0] = p[0]; u.i[1] = p[1]; u.i[2] = p[2]; u.i[3] = p[3];
  return u.v;
}

// ---------------------------------------------------------------------------
// Packed-weight layout: fragment = 64 lanes x 8 bf16. A[m][k]: m=lane&15,
// k=8*(lane>>4)+j.
//   P1 (r*16+t): W1[r][k][16t+m] (k>=22 -> 0)
//   P2 ((r*16+t)*8+c): W2[r][32c+k'][16t+m]
//   P3 (r*8+c): W3[r][32c+k'][fm(m)], fm(m)=8*((m>>2)&1)+4*(m>>3)+(m&3)
//   so lane (q,ln) C-output elem e = state feature 8*(q&1)+4*(q>>1)+e.
// ---------------------------------------------------------------------------
#define N1G (64*16*64)
#define N2G (64*16*8*64)
#define N3G (64*8*64)

__global__ void pack_w(const float* __restrict__ W1,
                       const float* __restrict__ W2,
                       const float* __restrict__ W3,
                       unsigned short* __restrict__ P) {
  int gid = blockIdx.x * blockDim.x + threadIdx.x;
  if (gid >= N1G + N2G + N3G) return;
  unsigned short v[8];
  unsigned short* dst;
  if (gid < N1G) {
    int lane = gid & 63, t = (gid >> 6) & 15, r = gid >> 10;
    int qq = lane >> 4, mm = lane & 15;
    #pragma unroll
    for (int j = 0; j < 8; ++j) {
      int k = 8*qq + j;
      v[j] = (k < 22) ? bfbits((__bf16)W1[(r*22 + k)*256 + 16*t + mm]) : (unsigned short)0;
    }
    dst = P + (size_t)gid * 8;
  } else if (gid < N1G + N2G) {
    int g = gid - N1G;
    int lane = g & 63, c = (g >> 6) & 7, t = (g >> 9) & 15, r = g >> 13;
    int qq = lane >> 4, mm = lane & 15;
    #pragma unroll
    for (int j = 0; j < 8; ++j) {
      int k = 32*c + 8*qq + j;
      v[j] = bfbits((__bf16)W2[((size_t)r*256 + k)*256 + 16*t + mm]);
    }
    dst = P + (size_t)(N1G + g) * 8;
  } else {
    int g = gid - N1G - N2G;
    int lane = g & 63, c = (g >> 6) & 7, r = g >> 9;
    int qq = lane >> 4, mm = lane & 15;
    int fm = 8*((mm >> 2) & 1) + 4*(mm >> 3) + (mm & 3);   // row perm
    #pragma unroll
    for (int j = 0; j < 8; ++j) {
      int k = 32*c + 8*qq + j;
      v[j] = bfbits((__bf16)W3[(r*256 + k)*16 + fm]);
    }
    dst = P + (size_t)(N1G + N2G + g) * 8;
  }
  ushort4v lo = { v[0],v[1],v[2],v[3] }, hi = { v[4],v[5],v[6],v[7] };
  *(ushort4v*)dst = lo;
  *(ushort4v*)(dst + 4) = hi;
}

// ---------------------------------------------------------------------------
#define NG 2     // row-groups per block
#define SH 264   // h row stride (ushorts)
#define SM 68    // msg row stride (ushorts)

__global__ __launch_bounds__(256, 3) void md5_main(
    const float* __restrict__ msg,   // (16384,64)
    const float* __restrict__ st0,   // (16384,16)
    const float* __restrict__ b1,    // (64,256)
    const float* __restrict__ b2,    // (64,256)
    const float* __restrict__ b3,    // (64,16)
    const unsigned short* __restrict__ P,
    float* __restrict__ out)         // (16384,16)
{
  __shared__ unsigned short hA[NG][16][SH], hB[NG][16][SH];
  __shared__ unsigned short msgb[NG*16][SM], msgl[NG*16][SM];

  const int tid  = threadIdx.x;
  const int wv   = tid >> 6;
  const int lane = tid & 63;
  const int q    = lane >> 4;
  const int ln   = lane & 15;
  const int row0 = blockIdx.x * (NG*16);
  const int oPerm = 8*(q & 1) + 4*(q >> 1);   // this lane's feature base
  const bool isQ2 = (q == 2), isQ3 = (q == 3);

  const unsigned short* P1 = P;
  const unsigned short* P2 = P + (size_t)N1G * 8;
  const unsigned short* P3 = P + (size_t)(N1G + N2G) * 8;

  // msg preload (hi/lo split): 32 rows x 64 = 2048 elems / 256 thr = 8 each
  {
    int idx = tid * 8, rr = idx >> 6, cc = idx & 63;
    floatx4 v0 = *(const floatx4*)(msg + (size_t)(row0 + rr)*64 + cc);
    floatx4 v1 = *(const floatx4*)(msg + (size_t)(row0 + rr)*64 + cc + 4);
    #pragma unroll
    for (int j = 0; j < 4; ++j) {
      unsigned short h0 = bfbits((__bf16)v0[j]);
      unsigned short h1 = bfbits((__bf16)v1[j]);
      msgb[rr][cc + j]     = h0;
      msgb[rr][cc + 4 + j] = h1;
      msgl[rr][cc + j]     = bfbits((__bf16)(v0[j] - bf2f(h0)));
      msgl[rr][cc + 4 + j] = bfbits((__bf16)(v1[j] - bf2f(h1)));
    }
  }
  __syncthreads();

  // Current-round L1 B-fragments (registers)
  Frag fx[NG];
  {
    int sc = c_sched[0];
    float i1 = c_shift[0] * 0.04f;
    unsigned short i1h = bfbits((__bf16)i1);
    unsigned short i1l = bfbits((__bf16)(i1 - bf2f(i1h)));
    int i01h = pack2(0, i1h);   // i0 = 0 at round 0
    int i01l = pack2(0, i1l);
    #pragma unroll
    for (int g = 0; g < NG; ++g) {
      floatx4 s = *(const floatx4*)(st0 + (size_t)(row0 + g*16 + ln)*16 + oPerm);
      int2 wh = *(const int2*)&msgb[g*16 + ln][4*sc];
      int2 wl = *(const int2*)&msgl[g*16 + ln][4*sc];
      fx[g] = build_frag(s, wh.x, wh.y, wl.x, wl.y, i01h, i01l, isQ2, isQ3);
    }
  }

  #pragma unroll 1
  for (int r = 0; r < 64; ++r) {
    // -------- Layer 1: x (regs) @ W1 -> h1 (bf16, shared) --------
    floatx4 bb1[4];
    bf16x8  a1[4];
    const unsigned short* p1 = P1 + ((size_t)(r*16 + 4*wv)*64 + lane)*8;
    #pragma unroll
    for (int tt = 0; tt < 4; ++tt) {
      a1[tt]  = *(const bf16x8*)(p1 + (size_t)tt*512);
      bb1[tt] = *(const floatx4*)(b1 + r*256 + (4*wv + tt)*16 + 4*q);
    }
    #pragma unroll
    for (int tt = 0; tt < 4; ++tt) {
      int f0 = (4*wv + tt)*16 + 4*q;
      #pragma unroll
      for (int g = 0; g < NG; ++g) {
        floatx4 acc = bb1[tt];
        acc = mfma16(a1[tt], frag2v(fx[g].l), acc);
        acc = mfma16(a1[tt], frag2v(fx[g].h), acc);
        ushort4v h4;
        #pragma unroll
        for (int e = 0; e < 4; ++e) h4[e] = bfbits((__bf16)gelu_f(acc[e]));
        *(ushort4v*)&hA[g][ln][f0] = h4;
      }
    }
    __syncthreads();                       // (B) h1 ready; hB free

    // -------- Layer 2: h1 @ W2 -> h2 (bf16, shared) --------
    // B-frags read from LDS per-MFMA (no 64-reg preload -> no spill)
    floatx4 bb2[4];
    #pragma unroll
    for (int tt = 0; tt < 4; ++tt)
      bb2[tt] = *(const floatx4*)(b2 + r*256 + (4*wv + tt)*16 + 4*q);

    int2 wh[NG], wl[NG];
    int i01h = 0, i01l = 0;
    if (r < 63) {
      int sc = c_sched[r+1];
      float i0 = (float)(r+1) * 0.015625f;          // exact in bf16
      float i1 = c_shift[r+1] * 0.04f;
      unsigned short i1h = bfbits((__bf16)i1);
      unsigned short i1l = bfbits((__bf16)(i1 - bf2f(i1h)));
      i01h = pack2(bfbits((__bf16)i0), i1h);
      i01l = pack2(0, i1l);
      #pragma unroll
      for (int g = 0; g < NG; ++g) {
        wh[g] = *(const int2*)&msgb[g*16 + ln][4*sc];
        wl[g] = *(const int2*)&msgl[g*16 + ln][4*sc];
      }
    }

    const unsigned short* p2 = P2 + ((size_t)((r*16 + 4*wv)*8)*64 + lane)*8;
    #pragma unroll
    for (int tt = 0; tt < 4; ++tt) {
      bf16x8 a2[8];
      #pragma unroll
      for (int c = 0; c < 8; ++c)
        a2[c] = *(const bf16x8*)(p2 + (size_t)(tt*8 + c)*512);
      int f0 = (4*wv + tt)*16 + 4*q;
      #pragma unroll
      for (int g = 0; g < NG; ++g) {
        floatx4 acc = bb2[tt];
        #pragma unroll
        for (int c = 0; c < 8; ++c) {
          bf16x8 bfr = *(const bf16x8*)&hA[g][ln][32*c + 8*q];
          acc = mfma16(a2[c], bfr, acc);
        }
        ushort4v h4;
        #pragma unroll
        for (int e = 0; e < 4; ++e) h4[e] = bfbits((__bf16)gelu_f(acc[e]));
        *(ushort4v*)&hB[g][ln][f0] = h4;
      }
    }
    __syncthreads();                       // (C) h2 ready

    // -------- Layer 3 (redundant on every wave): h2 @ W3p -> state --------
    {
      bf16x8 a3[8];
      const unsigned short* p3 = P3 + ((size_t)(r*8)*64 + lane)*8;
      #pragma unroll
      for (int c = 0; c < 8; ++c) a3[c] = *(const bf16x8*)(p3 + (size_t)c*512);
      floatx4 bb3 = *(const floatx4*)(b3 + r*16 + oPerm);
      #pragma unroll
      for (int g = 0; g < NG; ++g) {
        floatx4 s = bb3;
        #pragma unroll
        for (int c = 0; c < 8; ++c) {
          bf16x8 bh = *(const bf16x8*)&hB[g][ln][32*c + 8*q];
          s = mfma16(a3[c], bh, s);
        }
        if (r == 63) {
          if (wv == 0)
            *(floatx4*)(out + (size_t)(row0 + g*16 + ln)*16 + oPerm) = s;
        } else {
          fx[g] = build_frag(s, wh[g].x, wh[g].y, wl[g].x, wl[g].y,
                             i01h, i01l, isQ2, isQ3);
        }
      }
    }
    // no barrier: next L1 uses only registers (fx)
  }
}

// ---------------------------------------------------------------------------
extern "C" void kernel_launch(void* const* d_in, const int* in_sizes, int n_in,
                              void* d_out, int out_size, void* d_ws, size_t ws_size,
                              hipStream_t stream) {
  const float* msg = (const float*)d_in[0];
  const float* st0 = (const float*)d_in[1];
  const float* W1  = (const float*)d_in[2];
  const float* b1  = (const float*)d_in[3];
  const float* W2  = (const float*)d_in[4];
  const float* b2  = (const float*)d_in[5];
  const float* W3  = (const float*)d_in[6];
  const float* b3  = (const float*)d_in[7];
  float* out = (float*)d_out;
  (void)in_sizes; (void)n_in; (void)out_size; (void)ws_size;

  unsigned short* P = (unsigned short*)d_ws;
  const int totalGroups = N1G + N2G + N3G;   // 622592
  pack_w<<<(totalGroups + 255) / 256, 256, 0, stream>>>(W1, W2, W3, P);
  md5_main<<<512, 256, 0, stream>>>(msg, st0, b1, b2, b3, P, out);
}